// Round 10
// baseline (344.958 us; speedup 1.0000x reference)
//
#include <hip/hip_runtime.h>
#include <hip/hip_bf16.h>

typedef __attribute__((ext_vector_type(8))) short short8;
typedef __attribute__((ext_vector_type(4))) float floatx4;

#define MFMA16(a, b, c) __builtin_amdgcn_mfma_f32_16x16x32_bf16((a), (b), (c), 0, 0, 0)

// Problem dims (fixed by setup_inputs)
static constexpr int Bb = 32, Nn = 864, Cc = 768, Hh = 12;
static constexpr int Mm = Bb * Nn;      // 27648
static constexpr int NKV = 2 * Cc;      // 1536 (K block then V block)
static constexpr int KVROWS = 256;      // padded KV rows per batch (216 used)

__device__ __forceinline__ void gload_lds16(const __hip_bfloat16* g, __hip_bfloat16* l) {
    __builtin_amdgcn_global_load_lds((const __attribute__((address_space(1))) void*)g,
                                     (__attribute__((address_space(3))) void*)l, 16, 0, 0);
}

// ---------------- fused prep: x cvt f32->bf16, W transposes+cvt ----------------
static constexpr int CVT_BLKS = (Mm * Cc / 4) / 256;             // 20736
static constexpr int TQKV_BLKS = (3 * Cc / 32) * (Cc / 32);      // 1728
static constexpr int TPROJ_BLKS = (Cc / 32) * (Cc / 32);         // 576

__global__ __launch_bounds__(256) void prep_kernel(const float* __restrict__ x,
                                                   const float* __restrict__ Wqkv,
                                                   const float* __restrict__ Wproj,
                                                   __hip_bfloat16* __restrict__ xb,
                                                   __hip_bfloat16* __restrict__ WqkvT,
                                                   __hip_bfloat16* __restrict__ WprojT) {
    __shared__ float tile[32][33];
    const int bx = blockIdx.x;
    if (bx < CVT_BLKS) {
        const int i = bx * 256 + threadIdx.x;
        const float4 v = ((const float4*)x)[i];
        __hip_bfloat16 o[4] = {__float2bfloat16(v.x), __float2bfloat16(v.y),
                               __float2bfloat16(v.z), __float2bfloat16(v.w)};
        ((uint2*)xb)[i] = *(const uint2*)o;
        return;
    }
    const float* in;
    __hip_bfloat16* out;
    int R, C, bid;
    if (bx < CVT_BLKS + TQKV_BLKS) {
        bid = bx - CVT_BLKS; in = Wqkv; out = WqkvT; R = Cc; C = 3 * Cc;
    } else {
        bid = bx - CVT_BLKS - TQKV_BLKS; in = Wproj; out = WprojT; R = Cc; C = Cc;
    }
    const int c0 = (bid % (C / 32)) * 32, r0 = (bid / (C / 32)) * 32;
    const int tx = threadIdx.x & 31, ty = threadIdx.x >> 5;
#pragma unroll
    for (int i = 0; i < 32; i += 8)
        tile[ty + i][tx] = in[(size_t)(r0 + ty + i) * C + c0 + tx];
    __syncthreads();
#pragma unroll
    for (int i = 0; i < 32; i += 8)
        out[(size_t)(c0 + ty + i) * R + r0 + tx] = __float2bfloat16(tile[tx][ty + i]);
}

// ---------------- 2-phase double-buffered GEMM core (T3 minimum recipe) --------
// BK=32 panels, As/Bs double-buffered (4x8KB = 32KB total, same 5-block LDS
// ceiling as m97). Stage of panel t+1 is issued BEFORE the ds_read+MFMA of
// panel t, so the __syncthreads() drain at step end lands after ~300cy of
// compute instead of immediately after issue (m97 staged then drained with
// ZERO overlap -> per-step load-latency stall, exposed at our low occupancy).
// Correctness: stage targets the free buffer; lgkmcnt(0) (compiler) moves LDS
// data to regs before the barrier, so re-staging buf[cur] next step can't race.
#define GEMM_STAGE(buf, kk)                                          \
    do {                                                             \
        gload_lds16(Ag + (kk),           &As[buf][(size_t)t * 8]);   \
        gload_lds16(Ag + (kk) + rsk,     &As[buf][2048 + (size_t)t * 8]); \
        gload_lds16(Bg + (kk),           &Bs[buf][(size_t)t * 8]);   \
        gload_lds16(Bg + (kk) + rsk,     &Bs[buf][2048 + (size_t)t * 8]); \
    } while (0)

#define GEMM_COMPUTE(buf)                                                          \
    do {                                                                           \
        short8 af[4], bfr[4];                                                      \
        _Pragma("unroll") for (int i = 0; i < 4; i++)                              \
            af[i] = *(const short8*)&As[buf][(wm + i * 16 + ln) * 32 + quad * 8];  \
        _Pragma("unroll") for (int j = 0; j < 4; j++)                              \
            bfr[j] = *(const short8*)&Bs[buf][(wn + j * 16 + ln) * 32 + quad * 8]; \
        __builtin_amdgcn_s_setprio(1);                                             \
        _Pragma("unroll") for (int i = 0; i < 4; i++)                              \
            _Pragma("unroll") for (int j = 0; j < 4; j++)                          \
                acc[i][j] = MFMA16(af[i], bfr[j], acc[i][j]);                      \
        __builtin_amdgcn_s_setprio(0);                                             \
    } while (0)

// ---------------- fused Q+KV GEMM --------------------------------------------
static constexpr int QBLKS = 6 * (Mm / 128);             // 1296
static constexpr int KVBLKS = 12 * (Bb * KVROWS / 128);  // 768
static constexpr int QKV_NWG = QBLKS + KVBLKS;           // 2064, % 8 == 0

__global__ __launch_bounds__(256) void gemm_qkv2(const __hip_bfloat16* __restrict__ A,
                                                 const __hip_bfloat16* __restrict__ WqkvT,
                                                 __hip_bfloat16* __restrict__ Qbuf,
                                                 __hip_bfloat16* __restrict__ KVbuf) {
    __shared__ __align__(16) __hip_bfloat16 As[2][4096];  // [buf][row*32+col], 128x32
    __shared__ __align__(16) __hip_bfloat16 Bs[2][4096];

    const int braw = (int)blockIdx.x;
    const int sid = (braw & 7) * (QKV_NWG / 8) + (braw >> 3);  // bijective

    int arow0, orow0, btrow0, ncol0, Nout;
    __hip_bfloat16* Out;
    if (sid < QBLKS) {                 // Q: full M, N=768
        const int nt = sid % 6, mt = sid / 6;
        arow0 = mt * 128; orow0 = arow0;
        btrow0 = nt * 128; ncol0 = nt * 128;
        Out = Qbuf; Nout = Cc;
    } else {                           // K/V: rows [0,256) per batch, N=1536
        const int s = sid - QBLKS;
        const int nt = s % 12, mt = s / 12;
        const int bb = mt >> 1, keybase = (mt & 1) << 7;
        arow0 = bb * Nn + keybase;     // x rows [b*864, b*864+256)
        orow0 = bb * KVROWS + keybase; // packed per-batch KV rows
        btrow0 = Cc + nt * 128;        // WqkvT rows 768..2304 (K then V)
        ncol0 = nt * 128;
        Out = KVbuf; Nout = NKV;
    }

    const int t = threadIdx.x;
    const int lane = t & 63, wave = t >> 6;
    const int wm = (wave >> 1) * 64, wn = (wave & 1) * 64;
    const int ln = lane & 15, quad = lane >> 4;

    floatx4 acc[4][4] = {};

    // stage addressing: load k of {0,1} covers rows k*64 + t/4, col (t&3)*8
    const __hip_bfloat16* Ag = A + (size_t)(arow0 + (t >> 2)) * Cc + (t & 3) * 8;
    const __hip_bfloat16* Bg = WqkvT + (size_t)(btrow0 + (t >> 2)) * Cc + (t & 3) * 8;
    const size_t rsk = (size_t)64 * Cc;

    GEMM_STAGE(0, 0);
    __syncthreads();                    // implicit vmcnt(0) drain: panel 0 ready
    int cur = 0;
    for (int ks = 0; ks < 23; ks++) {   // 24 panels of BK=32
        GEMM_STAGE(cur ^ 1, (ks + 1) * 32);
        GEMM_COMPUTE(cur);
        __syncthreads();                // drains the overlapped stage; next ready
        cur ^= 1;
    }
    GEMM_COMPUTE(cur);                  // last panel, no prefetch

    // Epilogue. C/D layout: row = quad*4 + r, col = ln (verified m89/m91)
#pragma unroll
    for (int j = 0; j < 4; j++) {
        const int n = ncol0 + wn + j * 16 + ln;
#pragma unroll
        for (int i = 0; i < 4; i++) {
            const int mrow = orow0 + wm + i * 16 + quad * 4;
#pragma unroll
            for (int r = 0; r < 4; r++)
                Out[(size_t)(mrow + r) * Nout + n] = __float2bfloat16(acc[i][j][r]);
        }
    }
}

// ---------------- proj GEMM: C[M x 768] = A[M x 768] * BT^T + bias (f32 out) ---
__global__ __launch_bounds__(256) void gemm_proj(const __hip_bfloat16* __restrict__ A,
                                                 const __hip_bfloat16* __restrict__ BT,
                                                 float* __restrict__ Cout,
                                                 const float* __restrict__ bias) {
    __shared__ __align__(16) __hip_bfloat16 As[2][4096];
    __shared__ __align__(16) __hip_bfloat16 Bs[2][4096];
    const int gx = (int)gridDim.x;
    const int nwg = gx * (int)gridDim.y;
    const int braw = (int)blockIdx.y * gx + (int)blockIdx.x;
    const int sid = (braw & 7) * (nwg >> 3) + (braw >> 3);
    const int mt = sid / gx, nt = sid - mt * gx;
    const int m0 = mt << 7, n0 = nt * 128;
    const int t = threadIdx.x;
    const int lane = t & 63, wave = t >> 6;
    const int wm = (wave >> 1) * 64, wn = (wave & 1) * 64;
    const int ln = lane & 15, quad = lane >> 4;

    floatx4 acc[4][4] = {};
    const __hip_bfloat16* Ag = A + (size_t)(m0 + (t >> 2)) * Cc + (t & 3) * 8;
    const __hip_bfloat16* Bg = BT + (size_t)(n0 + (t >> 2)) * Cc + (t & 3) * 8;
    const size_t rsk = (size_t)64 * Cc;

    GEMM_STAGE(0, 0);
    __syncthreads();
    int cur = 0;
    for (int ks = 0; ks < 23; ks++) {
        GEMM_STAGE(cur ^ 1, (ks + 1) * 32);
        GEMM_COMPUTE(cur);
        __syncthreads();
        cur ^= 1;
    }
    GEMM_COMPUTE(cur);

#pragma unroll
    for (int j = 0; j < 4; j++) {
        const int n = n0 + wn + j * 16 + ln;
        const float bv = bias[n];
#pragma unroll
        for (int i = 0; i < 4; i++) {
            const int mrow = m0 + wm + i * 16 + quad * 4;
#pragma unroll
            for (int r = 0; r < 4; r++)
                Cout[(size_t)(mrow + r) * Cc + n] = acc[i][j][r] + bv;
        }
    }
}

// ---------------- fused cross attention: r2 structure + 2-q-tile ILP per wave --
// (unchanged from round 9; measured-good)
template <int L, int QOFF, int KVOFF, int NQT, int NCH>
__device__ __forceinline__ void attn_pair(const __hip_bfloat16* __restrict__ qb,
                                          const __hip_bfloat16* __restrict__ kv,
                                          __hip_bfloat16* __restrict__ attn,
                                          int qc, int h, int b,
                                          __hip_bfloat16* VTs) {
    constexpr int KPAD = NCH * 32;               // padded key count for PV: t 160, s 96
    constexpr int VSTR = KPAD + 8;               // LDS stride for VT rows
    constexpr int NPAIR = NQT / 2;               // t 9, s 18
    const int t = threadIdx.x, lane = t & 63, wave = t >> 6;
    const int ln = lane & 15, quad = lane >> 4;
    const __hip_bfloat16 z16 = __float2bfloat16(0.0f);

    const __hip_bfloat16* kbase = kv + (size_t)(b * KVROWS + KVOFF) * NKV + h * 64;
    const __hip_bfloat16* vbase = kbase + Cc;   // V block at column offset 768

    // stage V transposed: VT[dd][key'], keys zero-padded to KPAD, swizzled cols
    for (int c = t; c < KPAD * 8; c += 256) {
        const int key = c >> 3, s8 = c & 7, d0 = s8 * 8;
        const int colp = (key + 8 * s8) % KPAD;   // dd>>3 == s8 for all 8 stores
        if (key < L) {
            uint4 raw = *(const uint4*)(vbase + (size_t)key * NKV + d0);
            const __hip_bfloat16* pv = (const __hip_bfloat16*)&raw;
#pragma unroll
            for (int jj = 0; jj < 8; jj++) VTs[(d0 + jj) * VSTR + colp] = pv[jj];
        } else {
#pragma unroll
            for (int jj = 0; jj < 8; jj++) VTs[(d0 + jj) * VSTR + colp] = z16;
        }
    }
    __syncthreads();

    const int pt = qc * 4 + wave;
    if (pt >= NPAIR) return;  // no further barriers below

    const int qt0 = 2 * pt;
    const __hip_bfloat16* qrowA =
        qb + (size_t)(b * Nn + QOFF + qt0 * 16 + ln) * Cc + h * 64;
    const __hip_bfloat16* qrowB = qrowA + (size_t)16 * Cc;
    const short8 aqA0 = *(const short8*)(qrowA + quad * 8);
    const short8 aqA1 = *(const short8*)(qrowA + 32 + quad * 8);
    const short8 aqB0 = *(const short8*)(qrowB + quad * 8);
    const short8 aqB1 = *(const short8*)(qrowB + 32 + quad * 8);

    float dsA = 0.0f, dsB = 0.0f;
    floatx4 accA[4] = {}, accB[4] = {};
    constexpr float CSC = 0.18033688011112042f;  // 0.125 * log2(e)

#pragma unroll
    for (int ch = 0; ch < NCH; ch++) {
        unsigned int pkA[2][2], pkB[2][2];
#pragma unroll
        for (int ti2 = 0; ti2 < 2; ti2++) {
            const int ti = ch * 2 + ti2;
            if (ti * 16 >= L) {  // fully-invalid tile (compile-time)
                pkA[ti2][0] = 0u; pkA[ti2][1] = 0u;
                pkB[ti2][0] = 0u; pkB[ti2][1] = 0u;
                continue;
            }
            const __hip_bfloat16* krow = kbase + (size_t)(ti * 16 + ln) * NKV;
            const short8 k0 = *(const short8*)(krow + quad * 8);
            const short8 k1 = *(const short8*)(krow + 32 + quad * 8);
            floatx4 sA = {0.f, 0.f, 0.f, 0.f}, sB = {0.f, 0.f, 0.f, 0.f};
            sA = MFMA16(k0, aqA0, sA);
            sA = MFMA16(k1, aqA1, sA);
            sB = MFMA16(k0, aqB0, sB);
            sB = MFMA16(k1, aqB1, sB);
            float pA[4], pB[4];
#pragma unroll
            for (int r = 0; r < 4; r++) {
                float eA = exp2f(sA[r] * CSC);
                float eB = exp2f(sB[r] * CSC);
                if (ti * 16 + 16 > L) {                           // partial tile
                    if (ti * 16 + quad * 4 + r >= L) { eA = 0.0f; eB = 0.0f; }
                }
                pA[r] = eA; dsA += eA;
                pB[r] = eB; dsB += eB;
            }
            {
                const __hip_bfloat162 lo = __float22bfloat162_rn(make_float2(pA[0], pA[1]));
                const __hip_bfloat162 hi = __float22bfloat162_rn(make_float2(pA[2], pA[3]));
                pkA[ti2][0] = *(const unsigned int*)&lo;
                pkA[ti2][1] = *(const unsigned int*)&hi;
            }
            {
                const __hip_bfloat162 lo = __float22bfloat162_rn(make_float2(pB[0], pB[1]));
                const __hip_bfloat162 hi = __float22bfloat162_rn(make_float2(pB[2], pB[3]));
                pkB[ti2][0] = *(const unsigned int*)&lo;
                pkB[ti2][1] = *(const unsigned int*)&hi;
            }
        }
        // Redistribute: target lane (ln, quad) needs tile (quad>>1), keys from
        // source quads 2*(quad&1) and 2*(quad&1)+1 (4 bf16 each).
        const int srcA = ln + ((quad & 1) << 5);
        const int srcB = srcA + 16;
        const bool hi2 = quad >= 2;
        union { unsigned int u[4]; short8 v; } pfA, pfB;
        {
            const unsigned int c0 = (unsigned int)__shfl((int)pkA[0][0], srcA);
            const unsigned int c1 = (unsigned int)__shfl((int)pkA[0][1], srcA);
            const unsigned int c2 = (unsigned int)__shfl((int)pkA[0][0], srcB);
            const unsigned int c3 = (unsigned int)__shfl((int)pkA[0][1], srcB);
            const unsigned int d0 = (unsigned int)__shfl((int)pkA[1][0], srcA);
            const unsigned int d1 = (unsigned int)__shfl((int)pkA[1][1], srcA);
            const unsigned int d2 = (unsigned int)__shfl((int)pkA[1][0], srcB);
            const unsigned int d3 = (unsigned int)__shfl((int)pkA[1][1], srcB);
            pfA.u[0] = hi2 ? d0 : c0;
            pfA.u[1] = hi2 ? d1 : c1;
            pfA.u[2] = hi2 ? d2 : c2;
            pfA.u[3] = hi2 ? d3 : c3;
        }
        {
            const unsigned int c0 = (unsigned int)__shfl((int)pkB[0][0], srcA);
            const unsigned int c1 = (unsigned int)__shfl((int)pkB[0][1], srcA);
            const unsigned int c2 = (unsigned int)__shfl((int)pkB[0][0], srcB);
            const unsigned int c3 = (unsigned int)__shfl((int)pkB[0][1], srcB);
            const unsigned int d0 = (unsigned int)__shfl((int)pkB[1][0], srcA);
            const unsigned int d1 = (unsigned int)__shfl((int)pkB[1][1], srcA);
            const unsigned int d2 = (unsigned int)__shfl((int)pkB[1][0], srcB);
            const unsigned int d3 = (unsigned int)__shfl((int)pkB[1][1], srcB);
            pfB.u[0] = hi2 ? d0 : c0;
            pfB.u[1] = hi2 ? d1 : c1;
            pfB.u[2] = hi2 ? d2 : c2;
            pfB.u[3] = hi2 ? d3 : c3;
        }
        // O^T accumulate: lane holds O^T[dd = j*16 + quad*4 + r][q = ln].
        // V^T fragment shared by both chains (swizzled col, same as r2).
#pragma unroll
        for (int j = 0; j < 4; j++) {
            const int dd = j * 16 + ln;
            const int colp = (ch * 32 + quad * 8 + ((dd >> 3) << 3)) % KPAD;
            const short8 vt = *(const short8*)&VTs[dd * VSTR + colp];
            accA[j] = MFMA16(vt, pfA.v, accA[j]);
            accB[j] = MFMA16(vt, pfB.v, accB[j]);
        }
    }

    // Denominator: per-lane partials cover keys {quad*4+r over all tiles}, col q=ln.
    dsA += __shfl_xor(dsA, 16); dsA += __shfl_xor(dsA, 32);
    dsB += __shfl_xor(dsB, 16); dsB += __shfl_xor(dsB, 32);
    const float invA = 1.0f / dsA, invB = 1.0f / dsB;

    const size_t orowA = (size_t)(b * Nn + QOFF + qt0 * 16 + ln) * Cc + h * 64;
    const size_t orowB = orowA + (size_t)16 * Cc;
#pragma unroll
    for (int j = 0; j < 4; j++) {
        {
            const __hip_bfloat162 lo =
                __float22bfloat162_rn(make_float2(accA[j][0] * invA, accA[j][1] * invA));
            const __hip_bfloat162 hi =
                __float22bfloat162_rn(make_float2(accA[j][2] * invA, accA[j][3] * invA));
            uint2 o = make_uint2(*(const unsigned int*)&lo, *(const unsigned int*)&hi);
            *(uint2*)&attn[orowA + j * 16 + quad * 4] = o;
        }
        {
            const __hip_bfloat162 lo =
                __float22bfloat162_rn(make_float2(accB[j][0] * invB, accB[j][1] * invB));
            const __hip_bfloat162 hi =
                __float22bfloat162_rn(make_float2(accB[j][2] * invB, accB[j][3] * invB));
            uint2 o = make_uint2(*(const unsigned int*)&lo, *(const unsigned int*)&hi);
            *(uint2*)&attn[orowB + j * 16 + quad * 4] = o;
        }
    }
}

// 8 blocks per (b,h): qc in [0,3) = t-part (9 pairs over 12 wave-slots),
// qc in [3,8) = s-part (18 pairs over 20 wave-slots). 3072 blocks, % 8 == 0.
static constexpr int ATTN_NB = 8 * Hh * Bb;  // 3072

__global__ __launch_bounds__(256, 4) void attn_fused(const __hip_bfloat16* __restrict__ qb,
                                                     const __hip_bfloat16* __restrict__ kv,
                                                     __hip_bfloat16* __restrict__ attn) {
    __shared__ __align__(16) __hip_bfloat16 VTs[64 * 168];
    const int rid = (int)blockIdx.x + 8 * ((int)blockIdx.y + 12 * (int)blockIdx.z);
    const int vid = (rid & 7) * (ATTN_NB / 8) + (rid >> 3);
    const int qc = vid % 8, g = vid / 8;
    const int h = g % 12, bq = g / 12;
    if (qc < 3)
        attn_pair<144, 0, 72, 18, 5>(qb, kv, attn, qc, h, bq, VTs);
    else
        attn_pair<72, 288, 0, 36, 3>(qb, kv, attn, qc - 3, h, bq, VTs);
}

// ---------------- launch ----------------
extern "C" void kernel_launch(void* const* d_in, const int* in_sizes, int n_in,
                              void* d_out, int out_size, void* d_ws, size_t ws_size,
                              hipStream_t stream) {
    const float* x     = (const float*)d_in[0];
    const float* Wqkv  = (const float*)d_in[1];
    const float* Wproj = (const float*)d_in[2];
    const float* bproj = (const float*)d_in[3];
    float* out = (float*)d_out;

    // workspace layout (bytes):
    //   [0, 42467328)            x_bf16  (27648 x 768)   -- later reused as attn
    //   [42467328, 46006272)     WqkvT   (2304 x 768)
    //   [46006272, 47185920)     WprojT  (768 x 768)
    //   [47185920, 89653248)     Qbuf    (27648 x 768)
    //   [89653248, 114819072)    KVbuf   (32 x 256 x 1536)
    char* ws = (char*)d_ws;
    __hip_bfloat16* xb     = (__hip_bfloat16*)ws;
    __hip_bfloat16* WqkvT  = (__hip_bfloat16*)(ws + 42467328);
    __hip_bfloat16* WprojT = (__hip_bfloat16*)(ws + 46006272);
    __hip_bfloat16* Qbuf   = (__hip_bfloat16*)(ws + 47185920);
    __hip_bfloat16* KVbuf  = (__hip_bfloat16*)(ws + 89653248);
    __hip_bfloat16* attn   = (__hip_bfloat16*)ws;  // alias xb: x consumed before attention

    prep_kernel<<<CVT_BLKS + TQKV_BLKS + TPROJ_BLKS, 256, 0, stream>>>(x, Wqkv, Wproj, xb,
                                                                       WqkvT, WprojT);
    gemm_qkv2<<<QKV_NWG, 256, 0, stream>>>(xb, WqkvT, Qbuf, KVbuf);
    attn_fused<<<dim3(8, Hh, Bb), 256, 0, stream>>>(Qbuf, KVbuf, attn);
    gemm_proj<<<dim3(Cc / 128, Mm / 128), 256, 0, stream>>>(attn, WprojT, out, bproj);
}